// Round 6
// baseline (284.169 us; speedup 1.0000x reference)
//
#include <hip/hip_runtime.h>

// ---------------------------------------------------------------------------
// MambaBlock fused pipeline, MI355X (gfx950) — round 6
// B=2, L=1024, D_MODEL=1024, D_INNER=2048, D_STATE=16, D_CONV=4, DT_RANK=64
//
// Changes vs round 5 (theory: GEMM K-loops lose ~2.5x to the per-iteration
// vmcnt(0) drain at __syncthreads, unfilled at 1-2 blocks/CU):
//  * gemm128p: 4-buffer LDS ring (64 KB), prefetch distance 3, raw s_barrier
//    + asm fences + manual s_waitcnt vmcnt(12/8/4/0)  (m139 mechanism).
//    Loads for tile k are issued 3 iterations early -> drain hidden.
//  * gemm_skinny_splitk: software-pipelined register staging with raw
//    barriers + explicit lgkmcnt(0) (loads for tile k+1 issued before the
//    compute barrier of tile k).
//  * GEMM-out: OSPLIT 4 -> 2 (pipeline covers latency; reduce traffic halved).
//  * scans / conv / prep unchanged (proven).
// ---------------------------------------------------------------------------

typedef unsigned short u16;
typedef unsigned int   u32;

#define B_SZ 2
#define L_SZ 1024
#define DM   1024
#define DI   2048
#define DS   16
#define DTR  64
#define NXD  96      /* DTR + 2*DS */
#define NCHUNK 16
#define CL   64      /* chunk length: NCHUNK*CL = L */
#define KSPLIT 8     /* split-K for skinny x_dbl GEMM */
#define KC     256   /* 2048 / KSPLIT */
#define OSPLIT 2     /* split-K for GEMM-out */

typedef __bf16 bf16x8 __attribute__((ext_vector_type(8)));
typedef float  f32x4  __attribute__((ext_vector_type(4)));

__device__ __forceinline__ u16 f2bf(float f) {
    u32 x = __float_as_uint(f);
    x += 0x7fffu + ((x >> 16) & 1u);   // round-to-nearest-even
    return (u16)(x >> 16);
}
__device__ __forceinline__ float bf2f(u16 v) {
    return __uint_as_float(((u32)v) << 16);
}

__device__ __forceinline__ void gld_lds16(const u16* g, u16* l) {
    __builtin_amdgcn_global_load_lds(
        (const __attribute__((address_space(1))) u32*)g,
        (__attribute__((address_space(3))) u32*)l, 16, 0, 0);
}

// raw workgroup barrier WITHOUT the compiler's vmcnt(0) drain
__device__ __forceinline__ void wg_barrier() {
    __asm__ volatile("" ::: "memory");
    __builtin_amdgcn_s_barrier();
    __asm__ volatile("" ::: "memory");
}
// s_waitcnt immediates: vmcnt in [3:0]|[15:14], expcnt=7 (off), lgkmcnt=0xF (off)
#define WAIT_VM12() __builtin_amdgcn_s_waitcnt(0xF7C)
#define WAIT_VM8()  __builtin_amdgcn_s_waitcnt(0xF78)
#define WAIT_VM4()  __builtin_amdgcn_s_waitcnt(0xF74)
#define WAIT_VM0()  __builtin_amdgcn_s_waitcnt(0xF70)
#define WAIT_LGKM0() __builtin_amdgcn_s_waitcnt(0xC07F)

// ---------------------------------------------------------------------------
// Pipelined 128x128 GEMM: C = A[M,K] * BT[N,K]^T, BK=32, 4-buffer LDS ring,
// prefetch distance 3. 256 thr = 4 waves (2x2), wave = 64x64 (4x4 MFMA).
// gridDim.z = split-K planes (KCHUNK = K / gridDim.z, KCHUNK % 32 == 0).
// op==0: Cf fp32 plane per z; op==1: Cf = softplus(acc+bias[col]); op==2: Cb bf16.
// ---------------------------------------------------------------------------
__global__ __launch_bounds__(256) void gemm128p(
    const u16* __restrict__ A, const u16* __restrict__ BT,
    float* __restrict__ Cf, u16* __restrict__ Cb,
    const float* __restrict__ bias,
    int M, int N, int K, int KCHUNK, int op)
{
    __shared__ u16 As[4][128 * 32];   // 4 x 8 KB
    __shared__ u16 Bs[4][128 * 32];   // 4 x 8 KB

    const int tid  = threadIdx.x;
    const int wave = tid >> 6;
    const int lane = tid & 63;
    const int q    = lane >> 4;
    const int r16  = lane & 15;
    const int wm   = (wave & 1) * 64;
    const int wn   = (wave >> 1) * 64;
    const int m0   = blockIdx.y * 128;
    const int n0   = blockIdx.x * 128;
    const int kb   = blockIdx.z * KCHUNK;

    const u16* gA0 = A  + (size_t)(m0 + (tid >> 2))      * K + (tid & 3) * 8;
    const u16* gA1 = A  + (size_t)(m0 + 64 + (tid >> 2)) * K + (tid & 3) * 8;
    const u16* gB0 = BT + (size_t)(n0 + (tid >> 2))      * K + (tid & 3) * 8;
    const u16* gB1 = BT + (size_t)(n0 + 64 + (tid >> 2)) * K + (tid & 3) * 8;

    const int niter = KCHUNK >> 5;

    // prologue: prefetch up to 3 tiles
    const int pre = niter < 3 ? niter : 3;
    for (int p = 0; p < pre; ++p) {
        const int k0 = kb + p * 32;
        gld_lds16(gA0 + k0, &As[p][tid * 8]);
        gld_lds16(gA1 + k0, &As[p][2048 + tid * 8]);
        gld_lds16(gB0 + k0, &Bs[p][tid * 8]);
        gld_lds16(gB1 + k0, &Bs[p][2048 + tid * 8]);
    }

    f32x4 acc[4][4];
#pragma unroll
    for (int s = 0; s < 4; ++s)
#pragma unroll
        for (int j = 0; j < 4; ++j) acc[s][j] = (f32x4){0.f, 0.f, 0.f, 0.f};

    for (int it = 0; it < niter; ++it) {
        if (it + 3 < niter) {
            const int k0 = kb + (it + 3) * 32;
            const int bi = (it + 3) & 3;
            gld_lds16(gA0 + k0, &As[bi][tid * 8]);
            gld_lds16(gA1 + k0, &As[bi][2048 + tid * 8]);
            gld_lds16(gB0 + k0, &Bs[bi][tid * 8]);
            gld_lds16(gB1 + k0, &Bs[bi][2048 + tid * 8]);
            WAIT_VM12();                 // 16 in flight -> oldest tile (it) done
        } else if (it + 2 < niter) {
            WAIT_VM8();
        } else if (it + 1 < niter) {
            WAIT_VM4();
        } else {
            WAIT_VM0();
        }
        wg_barrier();                    // tile it valid for all threads

        const int cur = it & 3;
        bf16x8 af[4], bfr[4];
#pragma unroll
        for (int s = 0; s < 4; ++s)
            af[s] = *(const bf16x8*)(&As[cur][(wm + s * 16 + r16) * 32 + q * 8]);
#pragma unroll
        for (int j = 0; j < 4; ++j)
            bfr[j] = *(const bf16x8*)(&Bs[cur][(wn + j * 16 + r16) * 32 + q * 8]);
#pragma unroll
        for (int s = 0; s < 4; ++s)
#pragma unroll
            for (int j = 0; j < 4; ++j)
                acc[s][j] = __builtin_amdgcn_mfma_f32_16x16x32_bf16(
                    af[s], bfr[j], acc[s][j], 0, 0, 0);

        wg_barrier();                    // reads of buf(it) done before reuse
    }

#pragma unroll
    for (int s = 0; s < 4; ++s) {
        const int row0 = m0 + wm + s * 16 + q * 4;
#pragma unroll
        for (int j = 0; j < 4; ++j) {
            const int col = n0 + wn + j * 16 + r16;
            if (op == 0) {
                float* Cz = Cf + (size_t)blockIdx.z * M * N;
#pragma unroll
                for (int i = 0; i < 4; ++i)
                    Cz[(size_t)(row0 + i) * N + col] = acc[s][j][i];
            } else if (op == 1) {
                const float bv = bias[col];
#pragma unroll
                for (int i = 0; i < 4; ++i) {
                    float v = acc[s][j][i] + bv;
                    v = (v > 20.f) ? v : log1pf(__expf(v));
                    Cf[(size_t)(row0 + i) * N + col] = v;
                }
            } else {
#pragma unroll
                for (int i = 0; i < 4; ++i)
                    Cb[(size_t)(row0 + i) * N + col] = f2bf(acc[s][j][i]);
            }
        }
    }
}

// ---------------------------------------------------------------------------
// reduce GEMM-out split-K partials (OSPLIT planes of M*N) -> out, float4
// ---------------------------------------------------------------------------
__global__ __launch_bounds__(256) void reduce_out(
    const float* __restrict__ part, float* __restrict__ out, int n)
{
    const int i = (blockIdx.x * 256 + threadIdx.x) * 4;
    if (i >= n) return;
    f32x4 v = *(const f32x4*)(part + i);
#pragma unroll
    for (int s = 1; s < OSPLIT; ++s) {
        f32x4 p = *(const f32x4*)(part + (size_t)s * n + i);
        v.x += p.x; v.y += p.y; v.z += p.z; v.w += p.w;
    }
    *(f32x4*)(out + i) = v;
}

// ---------------------------------------------------------------------------
// Skinny-N split-K GEMM (x_dbl, N=96): 128x64x32 tile, register staging,
// software-pipelined (next tile's loads issued before compute barrier),
// raw barriers + explicit lgkmcnt(0).
// ---------------------------------------------------------------------------
__global__ __launch_bounds__(256) void gemm_skinny_splitk(
    const u16* __restrict__ A, const u16* __restrict__ BT,
    float* __restrict__ Cpart, int M, int N, int K)
{
    constexpr int LDT = 40;
    __shared__ u16 As[128 * LDT];
    __shared__ u16 Bs[64 * LDT];

    const int tid  = threadIdx.x;
    const int wave = tid >> 6;
    const int lane = tid & 63;
    const int q    = lane >> 4;
    const int r16  = lane & 15;
    const int m0   = blockIdx.y * 128;
    const int n0   = blockIdx.x * 64;
    const int kcs  = blockIdx.z * KC;
    const int sr   = tid >> 2;
    const int ss   = (tid & 3) * 8;

    f32x4 acc[2][4];
#pragma unroll
    for (int s = 0; s < 2; ++s)
#pragma unroll
        for (int j = 0; j < 4; ++j) acc[s][j] = (f32x4){0.f, 0.f, 0.f, 0.f};

    const int bcol  = n0 + sr;
    const int bcolc = bcol < N ? bcol : N - 1;   // clamp; garbage cols dropped

    constexpr int NIT = KC / 32;
    uint4 a0 = *(const uint4*)(A + (size_t)(m0 + sr)      * K + kcs + ss);
    uint4 a1 = *(const uint4*)(A + (size_t)(m0 + 64 + sr) * K + kcs + ss);
    uint4 bv = *(const uint4*)(BT + (size_t)bcolc * K + kcs + ss);

    for (int it = 0; it < NIT; ++it) {
        wg_barrier();                         // prev readers done, LDS free
        *(uint4*)(As + sr * LDT + ss)        = a0;
        *(uint4*)(As + (64 + sr) * LDT + ss) = a1;
        *(uint4*)(Bs + sr * LDT + ss)        = bv;
        // issue next tile's loads NOW (latency hidden behind compute)
        const int kn = (it + 1 < NIT) ? (kcs + (it + 1) * 32) : kcs;
        a0 = *(const uint4*)(A + (size_t)(m0 + sr)      * K + kn + ss);
        a1 = *(const uint4*)(A + (size_t)(m0 + 64 + sr) * K + kn + ss);
        bv = *(const uint4*)(BT + (size_t)bcolc * K + kn + ss);
        WAIT_LGKM0();                         // ds_writes visible
        wg_barrier();

        bf16x8 af[2], bfr[4];
#pragma unroll
        for (int s = 0; s < 2; ++s)
            af[s] = *(const bf16x8*)(As + (wave * 32 + s * 16 + r16) * LDT + q * 8);
#pragma unroll
        for (int j = 0; j < 4; ++j)
            bfr[j] = *(const bf16x8*)(Bs + (j * 16 + r16) * LDT + q * 8);
#pragma unroll
        for (int s = 0; s < 2; ++s)
#pragma unroll
            for (int j = 0; j < 4; ++j)
                acc[s][j] = __builtin_amdgcn_mfma_f32_16x16x32_bf16(
                    af[s], bfr[j], acc[s][j], 0, 0, 0);
    }

    float* Cp = Cpart + (size_t)blockIdx.z * M * N;
#pragma unroll
    for (int s = 0; s < 2; ++s) {
        const int row0 = m0 + wave * 32 + s * 16 + q * 4;
#pragma unroll
        for (int j = 0; j < 4; ++j) {
            const int col = n0 + j * 16 + r16;
            if (col < N) {
#pragma unroll
                for (int i = 0; i < 4; ++i)
                    Cp[(size_t)(row0 + i) * N + col] = acc[s][j][i];
            }
        }
    }
}

// ---------------------------------------------------------------------------
// reduce split-K partials -> xdbl fp32; also emit dt (cols 0..63) as bf16
// ---------------------------------------------------------------------------
__global__ __launch_bounds__(256) void reduce_xdbl(
    const float* __restrict__ part, float* __restrict__ xdbl,
    u16* __restrict__ dtbf)
{
    const int i = blockIdx.x * 256 + threadIdx.x;   // over 2048*96
    const int row = i / NXD, col = i - row * NXD;
    float v = 0.f;
#pragma unroll
    for (int s = 0; s < KSPLIT; ++s)
        v += part[(size_t)s * (B_SZ * L_SZ * NXD) + i];
    xdbl[i] = v;
    if (col < DTR) dtbf[row * DTR + col] = f2bf(v);
}

// ---------------------------------------------------------------------------
// fused prep: x cast + 4 weight transposes
// ---------------------------------------------------------------------------
__device__ __forceinline__ void tr_tile(
    const float* __restrict__ in, u16* __restrict__ out,
    int R, int C, int tr, int tc, int tid, float (*t)[33])
{
    const int tx = tid & 31, ty = tid >> 5;
    const int r0 = tr * 32, c0 = tc * 32;
#pragma unroll
    for (int i = 0; i < 4; ++i) {
        int r = r0 + ty + i * 8, c = c0 + tx;
        if (r < R && c < C) t[ty + i * 8][tx] = in[(size_t)r * C + c];
    }
    __syncthreads();
#pragma unroll
    for (int i = 0; i < 4; ++i) {
        int oR = c0 + ty + i * 8, oC = r0 + tx;
        if (oR < C && oC < R) out[(size_t)oR * R + oC] = f2bf(t[tx][ty + i * 8]);
    }
}

__global__ __launch_bounds__(256) void prep_kernel(
    const float* __restrict__ x,     u16* __restrict__ xbf,
    const float* __restrict__ W_in,  u16* __restrict__ winT,
    const float* __restrict__ W_out, u16* __restrict__ woutT,
    const float* __restrict__ W_x,   u16* __restrict__ wxT,
    const float* __restrict__ W_dt,  u16* __restrict__ wdtT)
{
    __shared__ float t[32][33];
    const int id  = blockIdx.x;
    const int tid = threadIdx.x;
    if (id < 4096) {                                   // W_in: 1024x4096
        tr_tile(W_in, winT, 1024, 4096, id >> 7, id & 127, tid, t);
    } else if (id < 6144) {                            // W_out: 2048x1024
        int i2 = id - 4096;
        tr_tile(W_out, woutT, 2048, 1024, i2 >> 5, i2 & 31, tid, t);
    } else if (id < 6336) {                            // W_x: 2048x96
        int i3 = id - 6144;
        tr_tile(W_x, wxT, 2048, 96, i3 / 3, i3 % 3, tid, t);
    } else if (id < 6464) {                            // W_dt: 64x2048
        int i4 = id - 6336;
        tr_tile(W_dt, wdtT, 64, 2048, i4 >> 6, i4 & 63, tid, t);
    } else {                                           // x cast: 2,097,152
        int i = (id - 6464) * 256 + tid;
        xbf[i] = f2bf(x[i]);
    }
}

// ---------------------------------------------------------------------------
// causal depthwise conv (D_CONV=4) + bias + silu; bf16 in (xz) / bf16 out (u)
// ---------------------------------------------------------------------------
__global__ __launch_bounds__(256) void conv_silu_kernel(
    const u16* __restrict__ xzbf, const float* __restrict__ cw,
    const float* __restrict__ cb, u16* __restrict__ ucbf)
{
    const int idx = blockIdx.x * 256 + threadIdx.x;   // over B*L*DI
    const int d   = idx & (DI - 1);
    const int pos = idx >> 11;                        // b*L + l
    const int l   = pos & (L_SZ - 1);
    float s = cb[d];
#pragma unroll
    for (int k = 0; k < 4; ++k) {
        int ls = l + k - 3;
        if (ls >= 0)
            s = fmaf(bf2f(xzbf[(size_t)(pos + k - 3) * (2 * DI) + d]), cw[d * 4 + k], s);
    }
    float v = s / (1.f + __expf(-s));   // silu
    ucbf[idx] = f2bf(v);
}

// ---------------------------------------------------------------------------
// Selective scan, 3-pass chunked (proven structure; bf16 u/z inputs)
// ---------------------------------------------------------------------------
__global__ __launch_bounds__(256) void scan_pass1(
    const float* __restrict__ delta, const u16* __restrict__ ucbf,
    const float* __restrict__ xdbl, const float* __restrict__ A_log,
    float* __restrict__ hbuf, float* __restrict__ pbuf)
{
    const int c = blockIdx.x;
    const int d = blockIdx.y * 256 + threadIdx.x;
    const int b = blockIdx.z;
    float Av[16], h[16], P[16];
#pragma unroll
    for (int n = 0; n < 16; ++n) {
        Av[n] = -__expf(A_log[d * 16 + n]);
        h[n] = 0.f; P[n] = 1.f;
    }
    const int rowbase = b * L_SZ + c * CL;
    for (int i = 0; i < CL; ++i) {
        const int row = rowbase + i;
        float dlt = delta[(size_t)row * DI + d];
        float uu  = bf2f(ucbf[(size_t)row * DI + d]);
        float du  = dlt * uu;
        const float* xr = xdbl + (size_t)row * NXD;   // block-uniform address
#pragma unroll
        for (int n = 0; n < 16; ++n) {
            float e = __expf(dlt * Av[n]);
            P[n] *= e;
            h[n] = fmaf(e, h[n], du * xr[DTR + n]);
        }
    }
    size_t base = ((size_t)((b * NCHUNK + c) * DI + d)) * 16;
#pragma unroll
    for (int n = 0; n < 16; ++n) { hbuf[base + n] = h[n]; pbuf[base + n] = P[n]; }
}

// parallel over (b, d*16+n): coalesced, 256 blocks
__global__ __launch_bounds__(256) void scan_pass2(
    float* __restrict__ hbuf, const float* __restrict__ pbuf)
{
    const int j = blockIdx.x * 256 + threadIdx.x;   // d*16+n in [0, 32768)
    const int b = blockIdx.y;
    float h0 = 0.f;
    for (int cc = 0; cc < NCHUNK; ++cc) {
        size_t o = ((size_t)(b * NCHUNK + cc)) * (DI * 16) + j;
        float hl = hbuf[o];
        float Pl = pbuf[o];
        hbuf[o] = h0;                  // h0 entering chunk cc
        h0 = fmaf(Pl, h0, hl);
    }
}

__global__ __launch_bounds__(256) void scan_pass3(
    const float* __restrict__ delta, const u16* __restrict__ ucbf,
    const float* __restrict__ xdbl, const float* __restrict__ A_log,
    const float* __restrict__ hbuf, const u16* __restrict__ xzbf,
    const float* __restrict__ Dskip, u16* __restrict__ ybf)
{
    const int c = blockIdx.x;
    const int d = blockIdx.y * 256 + threadIdx.x;
    const int b = blockIdx.z;
    float Av[16], h[16];
    size_t base = ((size_t)((b * NCHUNK + c) * DI + d)) * 16;
#pragma unroll
    for (int n = 0; n < 16; ++n) {
        Av[n] = -__expf(A_log[d * 16 + n]);
        h[n]  = hbuf[base + n];
    }
    const float Dk = Dskip[d];
    const int rowbase = b * L_SZ + c * CL;
    for (int i = 0; i < CL; ++i) {
        const int row = rowbase + i;
        float dlt = delta[(size_t)row * DI + d];
        float uu  = bf2f(ucbf[(size_t)row * DI + d]);
        float du  = dlt * uu;
        const float* xr = xdbl + (size_t)row * NXD;
        float y = 0.f;
#pragma unroll
        for (int n = 0; n < 16; ++n) {
            float e = __expf(dlt * Av[n]);
            h[n] = fmaf(e, h[n], du * xr[DTR + n]);
            y = fmaf(h[n], xr[DTR + DS + n], y);
        }
        float zz = bf2f(xzbf[(size_t)row * (2 * DI) + DI + d]);
        float yv = fmaf(uu, Dk, y) * (zz / (1.f + __expf(-zz)));
        ybf[(size_t)row * DI + d] = f2bf(yv);
    }
}

// ---------------------------------------------------------------------------
// workspace layout. SCRATCH (8,388,608 f) temporal overlays:
//   phase 4: xpart [0 .. 1,572,864)
//   phase 6: hbuf [0 .. 1,048,576), pbuf [1,048,576 .. 2,097,152)
//   phase 7: opart [0 .. 4,194,304)   (OSPLIT=2)
// ---------------------------------------------------------------------------
constexpr size_t OFF_DELTA   = 0;                          // 4,194,304 f
constexpr size_t OFF_XDBL    = OFF_DELTA + 4194304;        //   196,608 f
constexpr size_t OFF_SCRATCH = OFF_XDBL  + 196608;         // 8,388,608 f
constexpr size_t OFF_F32_END = OFF_SCRATCH + 8388608;
// bf16 region (u16 offsets from end of fp32 region)
constexpr size_t SOFF_XBF   = 0;                     // 2,097,152
constexpr size_t SOFF_WINT  = SOFF_XBF   + 2097152;  // 4,194,304
constexpr size_t SOFF_XZBF  = SOFF_WINT  + 4194304;  // 8,388,608
constexpr size_t SOFF_UCBF  = SOFF_XZBF  + 8388608;  // 4,194,304
constexpr size_t SOFF_WXT   = SOFF_UCBF  + 4194304;  //   196,608
constexpr size_t SOFF_DTBF  = SOFF_WXT   + 196608;   //   131,072
constexpr size_t SOFF_WDTT  = SOFF_DTBF  + 131072;   //   131,072
constexpr size_t SOFF_WOUTT = SOFF_WDTT  + 131072;   // 2,097,152
constexpr size_t SOFF_YBF   = SOFF_WOUTT + 2097152;  // 4,194,304

extern "C" void kernel_launch(void* const* d_in, const int* in_sizes, int n_in,
                              void* d_out, int out_size, void* d_ws, size_t ws_size,
                              hipStream_t stream)
{
    const float* x     = (const float*)d_in[0];
    const float* W_in  = (const float*)d_in[1];
    const float* cw    = (const float*)d_in[2];
    const float* cb    = (const float*)d_in[3];
    const float* W_x   = (const float*)d_in[4];
    const float* W_dt  = (const float*)d_in[5];
    const float* b_dt  = (const float*)d_in[6];
    const float* A_log = (const float*)d_in[7];
    const float* Dsk   = (const float*)d_in[8];
    const float* W_out = (const float*)d_in[9];
    float* out = (float*)d_out;

    float* wsf   = (float*)d_ws;
    float* dlt   = wsf + OFF_DELTA;
    float* xdbl  = wsf + OFF_XDBL;
    float* xpart = wsf + OFF_SCRATCH;                       // overlay (phase 4)
    float* hbuf  = wsf + OFF_SCRATCH;                       // overlay (phase 6)
    float* pbuf  = wsf + OFF_SCRATCH + 1048576;
    float* opart = wsf + OFF_SCRATCH;                       // overlay (phase 7)
    u16* sb    = (u16*)(wsf + OFF_F32_END);
    u16* xbf   = sb + SOFF_XBF;
    u16* winT  = sb + SOFF_WINT;
    u16* xzbf  = sb + SOFF_XZBF;
    u16* ucbf  = sb + SOFF_UCBF;
    u16* wxT   = sb + SOFF_WXT;
    u16* dtbf  = sb + SOFF_DTBF;
    u16* wdtT  = sb + SOFF_WDTT;
    u16* woutT = sb + SOFF_WOUTT;
    u16* ybf   = sb + SOFF_YBF;

    // 1) fused prep
    prep_kernel<<<14656, 256, 0, stream>>>(x, xbf, W_in, winT, W_out, woutT,
                                           W_x, wxT, W_dt, wdtT);

    // 2) xz = x @ W_in  (M=2048, N=4096, K=1024) -> bf16, 512 blocks
    gemm128p<<<dim3(32, 16, 1), 256, 0, stream>>>(
        xbf, winT, nullptr, xzbf, nullptr, 2048, 4096, 1024, 1024, 2);

    // 3) conv + silu (bf16 in/out)
    conv_silu_kernel<<<(B_SZ * L_SZ * DI) / 256, 256, 0, stream>>>(xzbf, cw, cb, ucbf);

    // 4) x_dbl = u @ W_x  (M=2048, N=96, K=2048) — split-K x8 + reduce
    gemm_skinny_splitk<<<dim3(2, 16, KSPLIT), 256, 0, stream>>>(
        ucbf, wxT, xpart, 2048, NXD, 2048);
    reduce_xdbl<<<(B_SZ * L_SZ * NXD) / 256, 256, 0, stream>>>(xpart, xdbl, dtbf);

    // 5) delta = softplus(dt @ W_dt + b_dt)  (M=2048, N=2048, K=64)
    gemm128p<<<dim3(16, 16, 1), 256, 0, stream>>>(
        dtbf, wdtT, dlt, nullptr, b_dt, 2048, 2048, 64, 64, 1);

    // 6) selective scan (3-pass chunked)
    scan_pass1<<<dim3(NCHUNK, DI / 256, B_SZ), 256, 0, stream>>>(dlt, ucbf, xdbl, A_log, hbuf, pbuf);
    scan_pass2<<<dim3(DI * 16 / 256, B_SZ), 256, 0, stream>>>(hbuf, pbuf);
    scan_pass3<<<dim3(NCHUNK, DI / 256, B_SZ), 256, 0, stream>>>(dlt, ucbf, xdbl, A_log, hbuf, xzbf, Dsk, ybf);

    // 7) out = y @ W_out  (M=2048, N=1024, K=2048) — split-K x2 + reduce
    gemm128p<<<dim3(8, 16, OSPLIT), 256, 0, stream>>>(
        ybf, woutT, opart, nullptr, nullptr, 2048, 1024, 2048, 2048 / OSPLIT, 0);
    reduce_out<<<(2048 * 1024 / 4 + 255) / 256, 256, 0, stream>>>(
        opart, out, 2048 * 1024);
}

// Round 7
// 262.860 us; speedup vs baseline: 1.0811x; 1.0811x over previous
//
#include <hip/hip_runtime.h>

// ---------------------------------------------------------------------------
// MambaBlock fused pipeline, MI355X (gfx950) — round 7
// B=2, L=1024, D_MODEL=1024, D_INNER=2048, D_STATE=16, D_CONV=4, DT_RANK=64
//
// Theory: trajectory responds to LAUNCH COUNT (~10 µs/dispatch), not kernel
// micro-opts. Changes vs round 6 (11 -> 9 launches, -70 MB glue traffic):
//  * skinny GEMM epilogue atomicAdd -> xdbl directly (kills reduce_xdbl,
//    xpart, dtbf; prep zeroes xdbl).
//  * delta GEMM stages A from fp32 xdbl with on-the-fly bf16 cast.
//  * GEMM-out: single kernel, 128x64 tiles, 256 blocks, ring-pipelined,
//    direct fp32 writes (kills reduce_out + opart).
//  * scans: NCHUNK 16 -> 32 (2 blocks/CU, 2 waves/SIMD latency hiding).
// ---------------------------------------------------------------------------

typedef unsigned short u16;
typedef unsigned int   u32;

#define B_SZ 2
#define L_SZ 1024
#define DM   1024
#define DI   2048
#define DS   16
#define DTR  64
#define NXD  96      /* DTR + 2*DS */
#define NCHUNK 32
#define CL   32      /* chunk length: NCHUNK*CL = L */
#define KSPLIT 8     /* split-K for skinny x_dbl GEMM */
#define KC     256   /* 2048 / KSPLIT */

typedef __bf16 bf16x8 __attribute__((ext_vector_type(8)));
typedef float  f32x4  __attribute__((ext_vector_type(4)));

__device__ __forceinline__ u16 f2bf(float f) {
    u32 x = __float_as_uint(f);
    x += 0x7fffu + ((x >> 16) & 1u);   // round-to-nearest-even
    return (u16)(x >> 16);
}
__device__ __forceinline__ float bf2f(u16 v) {
    return __uint_as_float(((u32)v) << 16);
}

__device__ __forceinline__ void gld_lds16(const u16* g, u16* l) {
    __builtin_amdgcn_global_load_lds(
        (const __attribute__((address_space(1))) u32*)g,
        (__attribute__((address_space(3))) u32*)l, 16, 0, 0);
}

// raw workgroup barrier WITHOUT the compiler's vmcnt(0) drain
__device__ __forceinline__ void wg_barrier() {
    __asm__ volatile("" ::: "memory");
    __builtin_amdgcn_s_barrier();
    __asm__ volatile("" ::: "memory");
}
// s_waitcnt immediates: vmcnt[3:0]|[15:14], expcnt=7 (off), lgkmcnt[11:8]=0xF (off)
#define WAIT_VM12() __builtin_amdgcn_s_waitcnt(0xF7C)
#define WAIT_VM9()  __builtin_amdgcn_s_waitcnt(0xF79)
#define WAIT_VM8()  __builtin_amdgcn_s_waitcnt(0xF78)
#define WAIT_VM6()  __builtin_amdgcn_s_waitcnt(0xF76)
#define WAIT_VM4()  __builtin_amdgcn_s_waitcnt(0xF74)
#define WAIT_VM3()  __builtin_amdgcn_s_waitcnt(0xF73)
#define WAIT_VM0()  __builtin_amdgcn_s_waitcnt(0xF70)

// ---------------------------------------------------------------------------
// Pipelined 128x128 GEMM (proven round-6): C = A[M,K]*BT[N,K]^T, BK=32,
// 4-buffer LDS ring, prefetch distance 3 (4 loads/iter -> waits 12/8/4/0).
// op==2: Cb bf16 out (only mode used this round).
// ---------------------------------------------------------------------------
__global__ __launch_bounds__(256) void gemm128p(
    const u16* __restrict__ A, const u16* __restrict__ BT,
    float* __restrict__ Cf, u16* __restrict__ Cb,
    int M, int N, int K, int op)
{
    __shared__ u16 As[4][128 * 32];
    __shared__ u16 Bs[4][128 * 32];

    const int tid  = threadIdx.x;
    const int wave = tid >> 6;
    const int lane = tid & 63;
    const int q    = lane >> 4;
    const int r16  = lane & 15;
    const int wm   = (wave & 1) * 64;
    const int wn   = (wave >> 1) * 64;
    const int m0   = blockIdx.y * 128;
    const int n0   = blockIdx.x * 128;

    const u16* gA0 = A  + (size_t)(m0 + (tid >> 2))      * K + (tid & 3) * 8;
    const u16* gA1 = A  + (size_t)(m0 + 64 + (tid >> 2)) * K + (tid & 3) * 8;
    const u16* gB0 = BT + (size_t)(n0 + (tid >> 2))      * K + (tid & 3) * 8;
    const u16* gB1 = BT + (size_t)(n0 + 64 + (tid >> 2)) * K + (tid & 3) * 8;

    const int niter = K >> 5;
    const int pre = niter < 3 ? niter : 3;
    for (int p = 0; p < pre; ++p) {
        const int k0 = p * 32;
        gld_lds16(gA0 + k0, &As[p][tid * 8]);
        gld_lds16(gA1 + k0, &As[p][2048 + tid * 8]);
        gld_lds16(gB0 + k0, &Bs[p][tid * 8]);
        gld_lds16(gB1 + k0, &Bs[p][2048 + tid * 8]);
    }

    f32x4 acc[4][4];
#pragma unroll
    for (int s = 0; s < 4; ++s)
#pragma unroll
        for (int j = 0; j < 4; ++j) acc[s][j] = (f32x4){0.f, 0.f, 0.f, 0.f};

    for (int it = 0; it < niter; ++it) {
        if (it + 3 < niter) {
            const int k0 = (it + 3) * 32;
            const int bi = (it + 3) & 3;
            gld_lds16(gA0 + k0, &As[bi][tid * 8]);
            gld_lds16(gA1 + k0, &As[bi][2048 + tid * 8]);
            gld_lds16(gB0 + k0, &Bs[bi][tid * 8]);
            gld_lds16(gB1 + k0, &Bs[bi][2048 + tid * 8]);
            WAIT_VM12();
        } else if (it + 2 < niter) {
            WAIT_VM8();
        } else if (it + 1 < niter) {
            WAIT_VM4();
        } else {
            WAIT_VM0();
        }
        wg_barrier();

        const int cur = it & 3;
        bf16x8 af[4], bfr[4];
#pragma unroll
        for (int s = 0; s < 4; ++s)
            af[s] = *(const bf16x8*)(&As[cur][(wm + s * 16 + r16) * 32 + q * 8]);
#pragma unroll
        for (int j = 0; j < 4; ++j)
            bfr[j] = *(const bf16x8*)(&Bs[cur][(wn + j * 16 + r16) * 32 + q * 8]);
#pragma unroll
        for (int s = 0; s < 4; ++s)
#pragma unroll
            for (int j = 0; j < 4; ++j)
                acc[s][j] = __builtin_amdgcn_mfma_f32_16x16x32_bf16(
                    af[s], bfr[j], acc[s][j], 0, 0, 0);

        wg_barrier();
    }

#pragma unroll
    for (int s = 0; s < 4; ++s) {
        const int row0 = m0 + wm + s * 16 + q * 4;
#pragma unroll
        for (int j = 0; j < 4; ++j) {
            const int col = n0 + wn + j * 16 + r16;
            if (op == 2) {
#pragma unroll
                for (int i = 0; i < 4; ++i)
                    Cb[(size_t)(row0 + i) * N + col] = f2bf(acc[s][j][i]);
            } else {
#pragma unroll
                for (int i = 0; i < 4; ++i)
                    Cf[(size_t)(row0 + i) * N + col] = acc[s][j][i];
            }
        }
    }
}

// ---------------------------------------------------------------------------
// GEMM-out: C[M,N] = A[M,K]*BT[N,K]^T, 128x64 tile, no split-K, direct fp32.
// 256 blocks (M/128=16 x N/64=16), 4-buf ring (48 KB), 3 loads/iter ->
// waits 9/6/3/0. Wave = 64x32 (4x2 MFMAs).
// ---------------------------------------------------------------------------
__global__ __launch_bounds__(256) void gemm_out64(
    const u16* __restrict__ A, const u16* __restrict__ BT,
    float* __restrict__ C, int M, int N, int K)
{
    __shared__ u16 As[4][128 * 32];   // 8 KB each
    __shared__ u16 Bs[4][64 * 32];    // 4 KB each

    const int tid  = threadIdx.x;
    const int wave = tid >> 6;
    const int lane = tid & 63;
    const int q    = lane >> 4;
    const int r16  = lane & 15;
    const int wm   = (wave & 1) * 64;
    const int wn   = (wave >> 1) * 32;
    const int m0   = blockIdx.y * 128;
    const int n0   = blockIdx.x * 64;

    const u16* gA0 = A  + (size_t)(m0 + (tid >> 2))      * K + (tid & 3) * 8;
    const u16* gA1 = A  + (size_t)(m0 + 64 + (tid >> 2)) * K + (tid & 3) * 8;
    const u16* gB0 = BT + (size_t)(n0 + (tid >> 2))      * K + (tid & 3) * 8;

    const int niter = K >> 5;
    const int pre = niter < 3 ? niter : 3;
    for (int p = 0; p < pre; ++p) {
        const int k0 = p * 32;
        gld_lds16(gA0 + k0, &As[p][tid * 8]);
        gld_lds16(gA1 + k0, &As[p][2048 + tid * 8]);
        gld_lds16(gB0 + k0, &Bs[p][tid * 8]);
    }

    f32x4 acc[4][2];
#pragma unroll
    for (int s = 0; s < 4; ++s)
#pragma unroll
        for (int j = 0; j < 2; ++j) acc[s][j] = (f32x4){0.f, 0.f, 0.f, 0.f};

    for (int it = 0; it < niter; ++it) {
        if (it + 3 < niter) {
            const int k0 = (it + 3) * 32;
            const int bi = (it + 3) & 3;
            gld_lds16(gA0 + k0, &As[bi][tid * 8]);
            gld_lds16(gA1 + k0, &As[bi][2048 + tid * 8]);
            gld_lds16(gB0 + k0, &Bs[bi][tid * 8]);
            WAIT_VM9();
        } else if (it + 2 < niter) {
            WAIT_VM6();
        } else if (it + 1 < niter) {
            WAIT_VM3();
        } else {
            WAIT_VM0();
        }
        wg_barrier();

        const int cur = it & 3;
        bf16x8 af[4], bfr[2];
#pragma unroll
        for (int s = 0; s < 4; ++s)
            af[s] = *(const bf16x8*)(&As[cur][(wm + s * 16 + r16) * 32 + q * 8]);
#pragma unroll
        for (int j = 0; j < 2; ++j)
            bfr[j] = *(const bf16x8*)(&Bs[cur][(wn + j * 16 + r16) * 32 + q * 8]);
#pragma unroll
        for (int s = 0; s < 4; ++s)
#pragma unroll
            for (int j = 0; j < 2; ++j)
                acc[s][j] = __builtin_amdgcn_mfma_f32_16x16x32_bf16(
                    af[s], bfr[j], acc[s][j], 0, 0, 0);

        wg_barrier();
    }

#pragma unroll
    for (int s = 0; s < 4; ++s) {
        const int row0 = m0 + wm + s * 16 + q * 4;
#pragma unroll
        for (int j = 0; j < 2; ++j) {
            const int col = n0 + wn + j * 16 + r16;
#pragma unroll
            for (int i = 0; i < 4; ++i)
                C[(size_t)(row0 + i) * N + col] = acc[s][j][i];
        }
    }
}

// ---------------------------------------------------------------------------
// Skinny-N split-K GEMM (x_dbl, N=96): 128x64x32, register staging, pipelined,
// epilogue atomicAdd into xdbl fp32 (xdbl zeroed by prep).
// ---------------------------------------------------------------------------
__global__ __launch_bounds__(256) void gemm_skinny_atomic(
    const u16* __restrict__ A, const u16* __restrict__ BT,
    float* xdbl, int M, int N, int K)
{
    constexpr int LDT = 40;
    __shared__ u16 As[128 * LDT];
    __shared__ u16 Bs[64 * LDT];

    const int tid  = threadIdx.x;
    const int wave = tid >> 6;
    const int lane = tid & 63;
    const int q    = lane >> 4;
    const int r16  = lane & 15;
    const int m0   = blockIdx.y * 128;
    const int n0   = blockIdx.x * 64;
    const int kcs  = blockIdx.z * KC;
    const int sr   = tid >> 2;
    const int ss   = (tid & 3) * 8;

    f32x4 acc[2][4];
#pragma unroll
    for (int s = 0; s < 2; ++s)
#pragma unroll
        for (int j = 0; j < 4; ++j) acc[s][j] = (f32x4){0.f, 0.f, 0.f, 0.f};

    const int bcol  = n0 + sr;
    const int bcolc = bcol < N ? bcol : N - 1;   // clamp; garbage cols dropped

    constexpr int NIT = KC / 32;
    uint4 a0 = *(const uint4*)(A + (size_t)(m0 + sr)      * K + kcs + ss);
    uint4 a1 = *(const uint4*)(A + (size_t)(m0 + 64 + sr) * K + kcs + ss);
    uint4 bv = *(const uint4*)(BT + (size_t)bcolc * K + kcs + ss);

    for (int it = 0; it < NIT; ++it) {
        wg_barrier();
        *(uint4*)(As + sr * LDT + ss)        = a0;
        *(uint4*)(As + (64 + sr) * LDT + ss) = a1;
        *(uint4*)(Bs + sr * LDT + ss)        = bv;
        const int kn = (it + 1 < NIT) ? (kcs + (it + 1) * 32) : kcs;
        a0 = *(const uint4*)(A + (size_t)(m0 + sr)      * K + kn + ss);
        a1 = *(const uint4*)(A + (size_t)(m0 + 64 + sr) * K + kn + ss);
        bv = *(const uint4*)(BT + (size_t)bcolc * K + kn + ss);
        __builtin_amdgcn_s_waitcnt(0xF70 | 0x0000);  // vmcnt ok; need lgkm drain:
        __builtin_amdgcn_s_waitcnt(0x070F);          // lgkmcnt(0) for ds_writes
        wg_barrier();

        bf16x8 af[2], bfr[4];
#pragma unroll
        for (int s = 0; s < 2; ++s)
            af[s] = *(const bf16x8*)(As + (wave * 32 + s * 16 + r16) * LDT + q * 8);
#pragma unroll
        for (int j = 0; j < 4; ++j)
            bfr[j] = *(const bf16x8*)(Bs + (j * 16 + r16) * LDT + q * 8);
#pragma unroll
        for (int s = 0; s < 2; ++s)
#pragma unroll
            for (int j = 0; j < 4; ++j)
                acc[s][j] = __builtin_amdgcn_mfma_f32_16x16x32_bf16(
                    af[s], bfr[j], acc[s][j], 0, 0, 0);
    }

#pragma unroll
    for (int s = 0; s < 2; ++s) {
        const int row0 = m0 + wave * 32 + s * 16 + q * 4;
#pragma unroll
        for (int j = 0; j < 4; ++j) {
            const int col = n0 + j * 16 + r16;
            if (col < N) {
#pragma unroll
                for (int i = 0; i < 4; ++i)
                    atomicAdd(&xdbl[(size_t)(row0 + i) * N + col], acc[s][j][i]);
            }
        }
    }
}

// ---------------------------------------------------------------------------
// delta GEMM: dlt[2048,2048] = softplus(xdbl[:, :64] @ wdtT^T + b_dt)
// A staged from fp32 xdbl (stride NXD) with on-the-fly bf16 cast; K=64.
// ---------------------------------------------------------------------------
__global__ __launch_bounds__(256) void gemm_delta(
    const float* __restrict__ xdbl, const u16* __restrict__ BT,
    const float* __restrict__ bias, float* __restrict__ dlt)
{
    constexpr int LDT = 40;
    __shared__ u16 As[128 * LDT];
    __shared__ u16 Bs[128 * LDT];

    const int tid  = threadIdx.x;
    const int wave = tid >> 6;
    const int lane = tid & 63;
    const int q    = lane >> 4;
    const int r16  = lane & 15;
    const int wm   = (wave & 1) * 64;
    const int wn   = (wave >> 1) * 64;
    const int m0   = blockIdx.y * 128;
    const int n0   = blockIdx.x * 128;
    const int sr   = tid >> 2;
    const int ss   = (tid & 3) * 8;

    f32x4 acc[4][4];
#pragma unroll
    for (int s = 0; s < 4; ++s)
#pragma unroll
        for (int j = 0; j < 4; ++j) acc[s][j] = (f32x4){0.f, 0.f, 0.f, 0.f};

    for (int k0 = 0; k0 < DTR; k0 += 32) {
        __syncthreads();
        // A: two rows (sr, sr+64) x 8 fp32 -> bf16
        f32x4 f0 = *(const f32x4*)(xdbl + (size_t)(m0 + sr) * NXD + k0 + ss);
        f32x4 f1 = *(const f32x4*)(xdbl + (size_t)(m0 + sr) * NXD + k0 + ss + 4);
        f32x4 f2 = *(const f32x4*)(xdbl + (size_t)(m0 + 64 + sr) * NXD + k0 + ss);
        f32x4 f3 = *(const f32x4*)(xdbl + (size_t)(m0 + 64 + sr) * NXD + k0 + ss + 4);
        uint4 bv0 = *(const uint4*)(BT + (size_t)(n0 + sr)      * DTR + k0 + ss);
        uint4 bv1 = *(const uint4*)(BT + (size_t)(n0 + 64 + sr) * DTR + k0 + ss);
        u16* pa0 = As + sr * LDT + ss;
        u16* pa1 = As + (64 + sr) * LDT + ss;
#pragma unroll
        for (int i = 0; i < 4; ++i) { pa0[i] = f2bf(f0[i]); pa0[4 + i] = f2bf(f1[i]); }
#pragma unroll
        for (int i = 0; i < 4; ++i) { pa1[i] = f2bf(f2[i]); pa1[4 + i] = f2bf(f3[i]); }
        *(uint4*)(Bs + sr * LDT + ss)        = bv0;
        *(uint4*)(Bs + (64 + sr) * LDT + ss) = bv1;
        __syncthreads();

        bf16x8 af[4], bfr[4];
#pragma unroll
        for (int s = 0; s < 4; ++s)
            af[s] = *(const bf16x8*)(As + (wm + s * 16 + r16) * LDT + q * 8);
#pragma unroll
        for (int j = 0; j < 4; ++j)
            bfr[j] = *(const bf16x8*)(Bs + (wn + j * 16 + r16) * LDT + q * 8);
#pragma unroll
        for (int s = 0; s < 4; ++s)
#pragma unroll
            for (int j = 0; j < 4; ++j)
                acc[s][j] = __builtin_amdgcn_mfma_f32_16x16x32_bf16(
                    af[s], bfr[j], acc[s][j], 0, 0, 0);
    }

#pragma unroll
    for (int s = 0; s < 4; ++s) {
        const int row0 = m0 + wm + s * 16 + q * 4;
#pragma unroll
        for (int j = 0; j < 4; ++j) {
            const int col = n0 + wn + j * 16 + r16;
            const float bv = bias[col];
#pragma unroll
            for (int i = 0; i < 4; ++i) {
                float v = acc[s][j][i] + bv;
                v = (v > 20.f) ? v : log1pf(__expf(v));
                dlt[(size_t)(row0 + i) * DI + col] = v;
            }
        }
    }
}

// ---------------------------------------------------------------------------
// fused prep: x cast + 4 weight transposes + zero xdbl (for atomics)
// ---------------------------------------------------------------------------
__device__ __forceinline__ void tr_tile(
    const float* __restrict__ in, u16* __restrict__ out,
    int R, int C, int tr, int tc, int tid, float (*t)[33])
{
    const int tx = tid & 31, ty = tid >> 5;
    const int r0 = tr * 32, c0 = tc * 32;
#pragma unroll
    for (int i = 0; i < 4; ++i) {
        int r = r0 + ty + i * 8, c = c0 + tx;
        if (r < R && c < C) t[ty + i * 8][tx] = in[(size_t)r * C + c];
    }
    __syncthreads();
#pragma unroll
    for (int i = 0; i < 4; ++i) {
        int oR = c0 + ty + i * 8, oC = r0 + tx;
        if (oR < C && oC < R) out[(size_t)oR * R + oC] = f2bf(t[tx][ty + i * 8]);
    }
}

__global__ __launch_bounds__(256) void prep_kernel(
    const float* __restrict__ x,     u16* __restrict__ xbf,
    const float* __restrict__ W_in,  u16* __restrict__ winT,
    const float* __restrict__ W_out, u16* __restrict__ woutT,
    const float* __restrict__ W_x,   u16* __restrict__ wxT,
    const float* __restrict__ W_dt,  u16* __restrict__ wdtT,
    float* __restrict__ xdbl)
{
    __shared__ float t[32][33];
    const int id  = blockIdx.x;
    const int tid = threadIdx.x;
    if (id < 4096) {                                   // W_in: 1024x4096
        tr_tile(W_in, winT, 1024, 4096, id >> 7, id & 127, tid, t);
    } else if (id < 6144) {                            // W_out: 2048x1024
        int i2 = id - 4096;
        tr_tile(W_out, woutT, 2048, 1024, i2 >> 5, i2 & 31, tid, t);
    } else if (id < 6336) {                            // W_x: 2048x96
        int i3 = id - 6144;
        tr_tile(W_x, wxT, 2048, 96, i3 / 3, i3 % 3, tid, t);
    } else if (id < 6464) {                            // W_dt: 64x2048
        int i4 = id - 6336;
        tr_tile(W_dt, wdtT, 64, 2048, i4 >> 6, i4 & 63, tid, t);
    } else if (id < 14656) {                           // x cast: 2,097,152
        int i = (id - 6464) * 256 + tid;
        xbf[i] = f2bf(x[i]);
    } else {                                           // zero xdbl: 196,608 f
        f32x4 z = (f32x4){0.f, 0.f, 0.f, 0.f};
        ((f32x4*)xdbl)[(size_t)(id - 14656) * 256 + tid] = z;
    }
}

// ---------------------------------------------------------------------------
// causal depthwise conv (D_CONV=4) + bias + silu; bf16 in (xz) / bf16 out (u)
// ---------------------------------------------------------------------------
__global__ __launch_bounds__(256) void conv_silu_kernel(
    const u16* __restrict__ xzbf, const float* __restrict__ cw,
    const float* __restrict__ cb, u16* __restrict__ ucbf)
{
    const int idx = blockIdx.x * 256 + threadIdx.x;   // over B*L*DI
    const int d   = idx & (DI - 1);
    const int pos = idx >> 11;                        // b*L + l
    const int l   = pos & (L_SZ - 1);
    float s = cb[d];
#pragma unroll
    for (int k = 0; k < 4; ++k) {
        int ls = l + k - 3;
        if (ls >= 0)
            s = fmaf(bf2f(xzbf[(size_t)(pos + k - 3) * (2 * DI) + d]), cw[d * 4 + k], s);
    }
    float v = s / (1.f + __expf(-s));   // silu
    ucbf[idx] = f2bf(v);
}

// ---------------------------------------------------------------------------
// Selective scan, 3-pass chunked, NCHUNK=32 (2 blocks/CU).
// ---------------------------------------------------------------------------
__global__ __launch_bounds__(256) void scan_pass1(
    const float* __restrict__ delta, const u16* __restrict__ ucbf,
    const float* __restrict__ xdbl, const float* __restrict__ A_log,
    float* __restrict__ hbuf, float* __restrict__ pbuf)
{
    const int c = blockIdx.x;
    const int d = blockIdx.y * 256 + threadIdx.x;
    const int b = blockIdx.z;
    float Av[16], h[16], P[16];
#pragma unroll
    for (int n = 0; n < 16; ++n) {
        Av[n] = -__expf(A_log[d * 16 + n]);
        h[n] = 0.f; P[n] = 1.f;
    }
    const int rowbase = b * L_SZ + c * CL;
    for (int i = 0; i < CL; ++i) {
        const int row = rowbase + i;
        float dlt = delta[(size_t)row * DI + d];
        float uu  = bf2f(ucbf[(size_t)row * DI + d]);
        float du  = dlt * uu;
        const float* xr = xdbl + (size_t)row * NXD;   // block-uniform address
#pragma unroll
        for (int n = 0; n < 16; ++n) {
            float e = __expf(dlt * Av[n]);
            P[n] *= e;
            h[n] = fmaf(e, h[n], du * xr[DTR + n]);
        }
    }
    size_t base = ((size_t)((b * NCHUNK + c) * DI + d)) * 16;
#pragma unroll
    for (int n = 0; n < 16; ++n) { hbuf[base + n] = h[n]; pbuf[base + n] = P[n]; }
}

// parallel over (b, d*16+n): coalesced
__global__ __launch_bounds__(256) void scan_pass2(
    float* __restrict__ hbuf, const float* __restrict__ pbuf)
{
    const int j = blockIdx.x * 256 + threadIdx.x;   // d*16+n in [0, 32768)
    const int b = blockIdx.y;
    float h0 = 0.f;
    for (int cc = 0; cc < NCHUNK; ++cc) {
        size_t o = ((size_t)(b * NCHUNK + cc)) * (DI * 16) + j;
        float hl = hbuf[o];
        float Pl = pbuf[o];
        hbuf[o] = h0;                  // h0 entering chunk cc
        h0 = fmaf(Pl, h0, hl);
    }
}

__global__ __launch_bounds__(256) void scan_pass3(
    const float* __restrict__ delta, const u16* __restrict__ ucbf,
    const float* __restrict__ xdbl, const float* __restrict__ A_log,
    const float* __restrict__ hbuf, const u16* __restrict__ xzbf,
    const float* __restrict__ Dskip, u16* __restrict__ ybf)
{
    const int c = blockIdx.x;
    const int d = blockIdx.y * 256 + threadIdx.x;
    const int b = blockIdx.z;
    float Av[16], h[16];
    size_t base = ((size_t)((b * NCHUNK + c) * DI + d)) * 16;
#pragma unroll
    for (int n = 0; n < 16; ++n) {
        Av[n] = -__expf(A_log[d * 16 + n]);
        h[n]  = hbuf[base + n];
    }
    const float Dk = Dskip[d];
    const int rowbase = b * L_SZ + c * CL;
    for (int i = 0; i < CL; ++i) {
        const int row = rowbase + i;
        float dlt = delta[(size_t)row * DI + d];
        float uu  = bf2f(ucbf[(size_t)row * DI + d]);
        float du  = dlt * uu;
        const float* xr = xdbl + (size_t)row * NXD;
        float y = 0.f;
#pragma unroll
        for (int n = 0; n < 16; ++n) {
            float e = __expf(dlt * Av[n]);
            h[n] = fmaf(e, h[n], du * xr[DTR + n]);
            y = fmaf(h[n], xr[DTR + DS + n], y);
        }
        float zz = bf2f(xzbf[(size_t)row * (2 * DI) + DI + d]);
        float yv = fmaf(uu, Dk, y) * (zz / (1.f + __expf(-zz)));
        ybf[(size_t)row * DI + d] = f2bf(yv);
    }
}

// ---------------------------------------------------------------------------
// workspace layout (f32 element offsets)
// ---------------------------------------------------------------------------
constexpr size_t OFF_DELTA   = 0;                          // 4,194,304 f
constexpr size_t OFF_XDBL    = OFF_DELTA + 4194304;        //   196,608 f
constexpr size_t OFF_HBUF    = OFF_XDBL  + 196608;         // 2,097,152 f
constexpr size_t OFF_PBUF    = OFF_HBUF  + 2097152;        // 2,097,152 f
constexpr size_t OFF_F32_END = OFF_PBUF  + 2097152;
// bf16 region (u16 offsets from end of fp32 region)
constexpr size_t SOFF_XBF   = 0;                     // 2,097,152
constexpr size_t SOFF_WINT  = SOFF_XBF   + 2097152;  // 4,194,304
constexpr size_t SOFF_XZBF  = SOFF_WINT  + 4194304;  // 8,388,608
constexpr size_t SOFF_UCBF  = SOFF_XZBF  + 8388608;  // 4,194,304
constexpr size_t SOFF_WXT   = SOFF_UCBF  + 4194304;  //   196,608
constexpr size_t SOFF_WDTT  = SOFF_WXT   + 196608;   //   131,072
constexpr size_t SOFF_WOUTT = SOFF_WDTT  + 131072;   // 2,097,152
constexpr size_t SOFF_YBF   = SOFF_WOUTT + 2097152;  // 4,194,304

extern "C" void kernel_launch(void* const* d_in, const int* in_sizes, int n_in,
                              void* d_out, int out_size, void* d_ws, size_t ws_size,
                              hipStream_t stream)
{
    const float* x     = (const float*)d_in[0];
    const float* W_in  = (const float*)d_in[1];
    const float* cw    = (const float*)d_in[2];
    const float* cb    = (const float*)d_in[3];
    const float* W_x   = (const float*)d_in[4];
    const float* W_dt  = (const float*)d_in[5];
    const float* b_dt  = (const float*)d_in[6];
    const float* A_log = (const float*)d_in[7];
    const float* Dsk   = (const float*)d_in[8];
    const float* W_out = (const float*)d_in[9];
    float* out = (float*)d_out;

    float* wsf   = (float*)d_ws;
    float* dlt   = wsf + OFF_DELTA;
    float* xdbl  = wsf + OFF_XDBL;
    float* hbuf  = wsf + OFF_HBUF;
    float* pbuf  = wsf + OFF_PBUF;
    u16* sb    = (u16*)(wsf + OFF_F32_END);
    u16* xbf   = sb + SOFF_XBF;
    u16* winT  = sb + SOFF_WINT;
    u16* xzbf  = sb + SOFF_XZBF;
    u16* ucbf  = sb + SOFF_UCBF;
    u16* wxT   = sb + SOFF_WXT;
    u16* wdtT  = sb + SOFF_WDTT;
    u16* woutT = sb + SOFF_WOUTT;
    u16* ybf   = sb + SOFF_YBF;

    // 1) fused prep (+ xdbl zeroing: 192 blocks of float4 stores)
    prep_kernel<<<14848, 256, 0, stream>>>(x, xbf, W_in, winT, W_out, woutT,
                                           W_x, wxT, W_dt, wdtT, xdbl);

    // 2) xz = x @ W_in  (M=2048, N=4096, K=1024) -> bf16, 512 blocks
    gemm128p<<<dim3(32, 16), 256, 0, stream>>>(
        xbf, winT, nullptr, xzbf, 2048, 4096, 1024, 2);

    // 3) conv + silu (bf16 in/out)
    conv_silu_kernel<<<(B_SZ * L_SZ * DI) / 256, 256, 0, stream>>>(xzbf, cw, cb, ucbf);

    // 4) x_dbl = u @ W_x  (M=2048, N=96, K=2048) — split-K x8, atomic into xdbl
    gemm_skinny_atomic<<<dim3(2, 16, KSPLIT), 256, 0, stream>>>(
        ucbf, wxT, xdbl, 2048, NXD, 2048);

    // 5) delta = softplus(xdbl[:, :64] @ W_dt + b_dt) -> dlt fp32
    gemm_delta<<<dim3(16, 16), 256, 0, stream>>>(xdbl, wdtT, b_dt, dlt);

    // 6) selective scan (3-pass chunked, NCHUNK=32)
    scan_pass1<<<dim3(NCHUNK, DI / 256, B_SZ), 256, 0, stream>>>(dlt, ucbf, xdbl, A_log, hbuf, pbuf);
    scan_pass2<<<dim3(DI * 16 / 256, B_SZ), 256, 0, stream>>>(hbuf, pbuf);
    scan_pass3<<<dim3(NCHUNK, DI / 256, B_SZ), 256, 0, stream>>>(dlt, ucbf, xdbl, A_log, hbuf, xzbf, Dsk, ybf);

    // 7) out = y @ W_out  (M=2048, N=1024, K=2048) — single kernel, direct fp32
    gemm_out64<<<dim3(16, 16), 256, 0, stream>>>(ybf, woutT, out, 2048, 1024, 2048);
}